// Round 4
// baseline (1017.126 us; speedup 1.0000x reference)
//
#include <hip/hip_runtime.h>
#include <stdint.h>

#define NN 50000
#define NE 800000
#define NG 64
#define CH 128
#define CO 16
#define KH 640   // 5 * 128

typedef __attribute__((ext_vector_type(8))) short bf16x8;
typedef __attribute__((ext_vector_type(4))) float f32x4;

__device__ __forceinline__ ushort f2bf(float f) {
  uint32_t u = __float_as_uint(f);
  u += 0x7fffu + ((u >> 16) & 1u);
  return (ushort)(u >> 16);
}
__device__ __forceinline__ float bflo(uint32_t v) { return __uint_as_float(v << 16); }
__device__ __forceinline__ float bfhi(uint32_t v) { return __uint_as_float(v & 0xffff0000u); }

// ---------------- graph preprocessing ----------------

__global__ void k_hist(const int* __restrict__ src, const int* __restrict__ dst,
                       int* __restrict__ deg, int* __restrict__ hist, int E) {
  int e = blockIdx.x * blockDim.x + threadIdx.x;
  if (e < E) {
    atomicAdd(&deg[src[e]], 1);
    atomicAdd(&hist[dst[e]], 1);
  }
}

__global__ __launch_bounds__(1024) void k_scan_a(const int* __restrict__ hist,
                                                 int* __restrict__ row_ptr,
                                                 int* __restrict__ bsum, int n) {
  __shared__ int sm[1024];
  int i = blockIdx.x * 1024 + threadIdx.x;
  int v = (i < n) ? hist[i] : 0;
  sm[threadIdx.x] = v;
  __syncthreads();
  for (int off = 1; off < 1024; off <<= 1) {
    int t = (threadIdx.x >= off) ? sm[threadIdx.x - off] : 0;
    __syncthreads();
    sm[threadIdx.x] += t;
    __syncthreads();
  }
  if (i < n) row_ptr[i + 1] = sm[threadIdx.x];
  if (threadIdx.x == 1023) bsum[blockIdx.x] = sm[1023];
}

__global__ void k_scan_b(int* __restrict__ bsum, int nb) {
  if (threadIdx.x == 0) {
    int off = 0;
    for (int i = 0; i < nb; ++i) { int t = bsum[i]; bsum[i] = off; off += t; }
  }
}

__global__ __launch_bounds__(1024) void k_scan_c(const int* __restrict__ bsum,
                                                 int* __restrict__ row_ptr, int n) {
  int i = blockIdx.x * 1024 + threadIdx.x;
  if (i == 0) row_ptr[0] = 0;
  if (i < n) row_ptr[i + 1] += bsum[blockIdx.x];
}

__global__ void k_scatter(const int* __restrict__ src, const int* __restrict__ dst,
                          const int* __restrict__ deg, const int* __restrict__ row_ptr,
                          int* __restrict__ fill, int2* __restrict__ esw, int E) {
  int e = blockIdx.x * blockDim.x + threadIdx.x;
  if (e < E) {
    int s = src[e], d = dst[e];
    int ds = deg[s], dd = deg[d];
    float di = ds > 0 ? rsqrtf((float)ds) : 0.f;
    float dj = dd > 0 ? rsqrtf((float)dd) : 0.f;
    float w = -di * dj;
    int pos = row_ptr[d] + atomicAdd(&fill[d], 1);
    int2 p; p.x = s; p.y = __float_as_int(w);
    esw[pos] = p;
  }
}

// ---------------- conversions ----------------

__global__ __launch_bounds__(256) void k_cvt_x(const float* __restrict__ x,
                                               ushort* __restrict__ buf) {
  int t = blockIdx.x * 256 + threadIdx.x;       // over NN*64 float2's
  if (t >= NN * 64) return;
  int node = t >> 6, p = t & 63;
  float2 v = reinterpret_cast<const float2*>(x)[t];
  uint32_t w = (uint32_t)f2bf(v.x) | ((uint32_t)f2bf(v.y) << 16);
  *reinterpret_cast<uint32_t*>(buf + (size_t)node * KH + p * 2) = w;
}

// W [640][cout] f32 -> Wt [cout][640] bf16
__global__ __launch_bounds__(256) void k_cvt_w(const float* __restrict__ W,
                                               ushort* __restrict__ Wt, int cout) {
  int t = blockIdx.x * 256 + threadIdx.x;
  if (t >= KH * cout) return;
  int kc = t / cout, nc = t - kc * cout;
  Wt[(size_t)nc * KH + kc] = f2bf(W[t]);
}

// W3 [5][128][16] f32 -> Wt3v [80][128] bf16 : Wt3v[k*16+j][c] = W3[k][c][j]
__global__ __launch_bounds__(256) void k_cvt_w3(const float* __restrict__ W,
                                                ushort* __restrict__ Wt) {
  int t = blockIdx.x * 256 + threadIdx.x;
  if (t >= 5 * CH * CO) return;
  int k = t / (CH * CO);
  int r = t - k * CH * CO;
  int c = r / CO, j = r - c * CO;
  Wt[(size_t)(k * CO + j) * CH + c] = f2bf(W[t]);
}

// ---------------- propagation (bf16, 128 ch), channel-chunked ----------------
// chunk of 32 channels (64B line) -> per-chunk working set 3.2MB, L2-resident.
// out = 2*L(hin) - tx0 (or L(hin) when tx0 == nullptr)

__global__ __launch_bounds__(256) void k_prop_c(
    const ushort* __restrict__ hin, const ushort* __restrict__ tx0,
    ushort* __restrict__ hout, const int* __restrict__ row_ptr,
    const int2* __restrict__ esw, int n) {
  int wave = threadIdx.x >> 6;
  int lane = threadIdx.x & 63;
  int nb = (n + 3) >> 2;                 // node-blocks per chunk
  int chunk = blockIdx.x / nb;           // 0..3  (chunk-major: XCD phase-locality)
  int nblk = blockIdx.x - chunk * nb;
  int node = nblk * 4 + wave;
  if (node >= n) return;
  int beg = row_ptr[node], end = row_ptr[node + 1];
  int grp = lane >> 4, li = lane & 15;   // 4 edge-groups x 16 lanes (2 ch each)
  const ushort* hc = hin + chunk * 32 + li * 2;

  float ax = 0.f, ay = 0.f;
  for (int e0 = beg; e0 < end; e0 += 8) {
    int ea = e0 + grp, eb = e0 + 4 + grp;
    int2 pa = esw[min(ea, NE - 1)];
    int2 pb = esw[min(eb, NE - 1)];
    float wa = (ea < end) ? __int_as_float(pa.y) : 0.f;
    float wb = (eb < end) ? __int_as_float(pb.y) : 0.f;
    uint32_t va = *reinterpret_cast<const uint32_t*>(hc + (size_t)pa.x * KH);
    uint32_t vb = *reinterpret_cast<const uint32_t*>(hc + (size_t)pb.x * KH);
    ax = fmaf(wa, bflo(va), ax);
    ay = fmaf(wa, bfhi(va), ay);
    ax = fmaf(wb, bflo(vb), ax);
    ay = fmaf(wb, bfhi(vb), ay);
  }
  // sum the 4 edge-groups: lanes l, l+16, l+32, l+48 hold the same channels
  ax += __shfl_xor(ax, 16, 64);
  ay += __shfl_xor(ay, 16, 64);
  ax += __shfl_xor(ax, 32, 64);
  ay += __shfl_xor(ay, 32, 64);

  if (grp == 0) {
    size_t o = (size_t)node * KH + chunk * 32 + li * 2;
    if (tx0) {
      uint32_t t0 = *reinterpret_cast<const uint32_t*>(tx0 + o);
      ax = 2.f * ax - bflo(t0);
      ay = 2.f * ay - bfhi(t0);
    }
    uint32_t w = (uint32_t)f2bf(ax) | ((uint32_t)f2bf(ay) << 16);
    *reinterpret_cast<uint32_t*>(hout + o) = w;
  }
}

// ---------------- propagation (bf16, 16 ch) with Clenshaw combine ----------------
// r = scale*L(gin) - prev + v  [+ bias -> f32 out]

__global__ __launch_bounds__(256) void k_prop16(
    const ushort* __restrict__ gin, int gstride,
    const ushort* __restrict__ prev, int pstride,
    const ushort* __restrict__ v, int vstride,
    const float* __restrict__ bias,
    ushort* __restrict__ bout, float* __restrict__ fout,
    float scale, const int* __restrict__ row_ptr,
    const int2* __restrict__ esw, int n) {
  int wave = threadIdx.x >> 6;
  int lane = threadIdx.x & 63;
  int node = blockIdx.x * 4 + wave;
  if (node >= n) return;
  int beg = row_ptr[node], end = row_ptr[node + 1];
  int ch2 = lane & 7;       // uint index over 16 channels
  int grp = lane >> 3;      // 8 edge subgroups
  float ax = 0.f, ay = 0.f;
  const ushort* gc = gin + ch2 * 2;
  for (int e = beg + grp; e < end; e += 8) {
    int2 p = esw[e];
    float w = __int_as_float(p.y);
    uint32_t vv = *reinterpret_cast<const uint32_t*>(gc + (size_t)p.x * gstride);
    ax = fmaf(w, bflo(vv), ax);
    ay = fmaf(w, bfhi(vv), ay);
  }
#pragma unroll
  for (int off = 8; off < 64; off <<= 1) {
    ax += __shfl_xor(ax, off, 64);
    ay += __shfl_xor(ay, off, 64);
  }
  if (lane < 8) {
    float rx = scale * ax, ry = scale * ay;
    if (prev) {
      uint32_t pv = *reinterpret_cast<const uint32_t*>(prev + (size_t)node * pstride + lane * 2);
      rx -= bflo(pv);
      ry -= bfhi(pv);
    }
    uint32_t vv = *reinterpret_cast<const uint32_t*>(v + (size_t)node * vstride + lane * 2);
    rx += bflo(vv);
    ry += bfhi(vv);
    if (fout) {
      fout[(size_t)node * CO + lane * 2]     = rx + bias[lane * 2];
      fout[(size_t)node * CO + lane * 2 + 1] = ry + bias[lane * 2 + 1];
    } else {
      uint32_t w = (uint32_t)f2bf(rx) | ((uint32_t)f2bf(ry) << 16);
      *reinterpret_cast<uint32_t*>(bout + (size_t)node * CO + lane * 2) = w;
    }
  }
}

// ---------------- MFMA GEMM: out slice = A[n x 640] @ W[640 x 128] + bias, relu

__global__ __launch_bounds__(256) void k_gemm_mfma128(
    const ushort* __restrict__ A, const ushort* __restrict__ Wt,
    const float* __restrict__ bias, ushort* __restrict__ outbf,
    int n, int dorelu) {
  int wave = threadIdx.x >> 6, lane = threadIdx.x & 63;
  int rowbase = blockIdx.x * 128 + wave * 32;
  int lr = lane & 15, lk = (lane >> 4) * 8;

  f32x4 acc[2][8];
#pragma unroll
  for (int r = 0; r < 2; ++r)
#pragma unroll
    for (int c = 0; c < 8; ++c) acc[r][c] = (f32x4){0.f, 0.f, 0.f, 0.f};

  int r0 = min(rowbase + lr, n - 1);
  int r1 = min(rowbase + 16 + lr, n - 1);
  const ushort* pa0 = A + (size_t)r0 * KH + lk;
  const ushort* pa1 = A + (size_t)r1 * KH + lk;
  const ushort* pb = Wt + (size_t)lr * KH + lk;

  for (int k0 = 0; k0 < KH; k0 += 32) {
    bf16x8 a0 = *reinterpret_cast<const bf16x8*>(pa0 + k0);
    bf16x8 a1 = *reinterpret_cast<const bf16x8*>(pa1 + k0);
#pragma unroll
    for (int c = 0; c < 8; ++c) {
      bf16x8 b = *reinterpret_cast<const bf16x8*>(pb + (size_t)c * 16 * KH + k0);
      acc[0][c] = __builtin_amdgcn_mfma_f32_16x16x32_bf16(a0, b, acc[0][c], 0, 0, 0);
      acc[1][c] = __builtin_amdgcn_mfma_f32_16x16x32_bf16(a1, b, acc[1][c], 0, 0, 0);
    }
  }

#pragma unroll
  for (int r = 0; r < 2; ++r) {
#pragma unroll
    for (int c = 0; c < 8; ++c) {
      int col = c * 16 + lr;
      float bs = bias[col];
#pragma unroll
      for (int i = 0; i < 4; ++i) {
        int row = rowbase + r * 16 + (lane >> 4) * 4 + i;
        if (row < n) {
          float v = acc[r][c][i] + bs;
          if (dorelu) v = fmaxf(v, 0.f);
          outbf[(size_t)row * KH + col] = f2bf(v);
        }
      }
    }
  }
}

// V[n x 80] bf16 = A[n x 128] @ Wt3v^T  (Wt3v [80][128])
__global__ __launch_bounds__(256) void k_gemm_v(
    const ushort* __restrict__ A, const ushort* __restrict__ Wt,
    ushort* __restrict__ V, int n) {
  int wave = threadIdx.x >> 6, lane = threadIdx.x & 63;
  int rowbase = blockIdx.x * 256 + wave * 64;
  int lr = lane & 15, lk = (lane >> 4) * 8;

  f32x4 acc[4][5];
#pragma unroll
  for (int r = 0; r < 4; ++r)
#pragma unroll
    for (int c = 0; c < 5; ++c) acc[r][c] = (f32x4){0.f, 0.f, 0.f, 0.f};

  const ushort* pa[4];
#pragma unroll
  for (int r = 0; r < 4; ++r) {
    int rr = min(rowbase + r * 16 + lr, n - 1);
    pa[r] = A + (size_t)rr * KH + lk;
  }
  const ushort* pb = Wt + (size_t)lr * CH + lk;

  for (int k0 = 0; k0 < CH; k0 += 32) {
    bf16x8 a[4];
#pragma unroll
    for (int r = 0; r < 4; ++r) a[r] = *reinterpret_cast<const bf16x8*>(pa[r] + k0);
#pragma unroll
    for (int c = 0; c < 5; ++c) {
      bf16x8 b = *reinterpret_cast<const bf16x8*>(pb + (size_t)c * 16 * CH + k0);
#pragma unroll
      for (int r = 0; r < 4; ++r)
        acc[r][c] = __builtin_amdgcn_mfma_f32_16x16x32_bf16(a[r], b, acc[r][c], 0, 0, 0);
    }
  }

#pragma unroll
  for (int r = 0; r < 4; ++r) {
#pragma unroll
    for (int c = 0; c < 5; ++c) {
      int col = c * 16 + lr;
#pragma unroll
      for (int i = 0; i < 4; ++i) {
        int row = rowbase + r * 16 + (lane >> 4) * 4 + i;
        if (row < n) V[(size_t)row * 80 + col] = f2bf(acc[r][c][i]);
      }
    }
  }
}

// ---------------- pooling + log_softmax ----------------

__global__ __launch_bounds__(256) void k_pool(
    const float* __restrict__ h, const int* __restrict__ batch,
    float* __restrict__ sums, float* __restrict__ cnts, int n) {
  __shared__ float sacc[NG * CO];
  __shared__ float scnt[NG];
  for (int i = threadIdx.x; i < NG * CO; i += 256) sacc[i] = 0.f;
  if (threadIdx.x < NG) scnt[threadIdx.x] = 0.f;
  __syncthreads();
  int ch = threadIdx.x & 15;
  int nl = threadIdx.x >> 4;
  int base = blockIdx.x * 1024;
  for (int i = 0; i < 64; ++i) {
    int node = base + i * 16 + nl;
    if (node < n) {
      int g = batch[node];
      atomicAdd(&sacc[g * CO + ch], h[(size_t)node * CO + ch]);
      if (ch == 0) atomicAdd(&scnt[g], 1.f);
    }
  }
  __syncthreads();
  for (int i = threadIdx.x; i < NG * CO; i += 256)
    if (sacc[i] != 0.f) atomicAdd(&sums[i], sacc[i]);
  if (threadIdx.x < NG && scnt[threadIdx.x] != 0.f)
    atomicAdd(&cnts[threadIdx.x], scnt[threadIdx.x]);
}

__global__ void k_lsm(const float* __restrict__ sums, const float* __restrict__ cnts,
                      float* __restrict__ out) {
  int g = threadIdx.x;
  if (g >= NG) return;
  float cnt = fmaxf(cnts[g], 1.f);
  float v[CO];
  float m = -1e30f;
#pragma unroll
  for (int c = 0; c < CO; ++c) { v[c] = sums[g * CO + c] / cnt; m = fmaxf(m, v[c]); }
  float s = 0.f;
#pragma unroll
  for (int c = 0; c < CO; ++c) s += expf(v[c] - m);
  float lse = m + logf(s);
#pragma unroll
  for (int c = 0; c < CO; ++c) out[g * CO + c] = v[c] - lse;
}

// ---------------- host ----------------

static void run_props(ushort* buf, const int* row_ptr, const int2* esw,
                      hipStream_t stream) {
  dim3 gp(((NN + 3) / 4) * 4);   // 4 chunks, chunk-major
  k_prop_c<<<gp, 256, 0, stream>>>(buf + 0 * CH, nullptr,      buf + 1 * CH, row_ptr, esw, NN);
  k_prop_c<<<gp, 256, 0, stream>>>(buf + 1 * CH, buf + 0 * CH, buf + 2 * CH, row_ptr, esw, NN);
  k_prop_c<<<gp, 256, 0, stream>>>(buf + 2 * CH, buf + 1 * CH, buf + 3 * CH, row_ptr, esw, NN);
  k_prop_c<<<gp, 256, 0, stream>>>(buf + 3 * CH, buf + 2 * CH, buf + 4 * CH, row_ptr, esw, NN);
}

extern "C" void kernel_launch(void* const* d_in, const int* in_sizes, int n_in,
                              void* d_out, int out_size, void* d_ws, size_t ws_size,
                              hipStream_t stream) {
  const float* x   = (const float*)d_in[0];
  const int* src   = (const int*)d_in[1];
  const int* dst   = (const int*)d_in[2];
  const int* batch = (const int*)d_in[3];
  const float* W1  = (const float*)d_in[4];
  const float* b1  = (const float*)d_in[5];
  const float* W2  = (const float*)d_in[6];
  const float* b2  = (const float*)d_in[7];
  const float* W3  = (const float*)d_in[8];
  const float* b3  = (const float*)d_in[9];
  float* out = (float*)d_out;

  char* p = (char*)d_ws;
  auto alloc = [&](size_t bytes) -> void* {
    void* r = (void*)p;
    p += (bytes + 511) & ~(size_t)511;
    return r;
  };
  int* deg     = (int*)alloc((size_t)NN * 4);
  int* hist    = (int*)alloc((size_t)NN * 4);
  int* fill    = (int*)alloc((size_t)NN * 4);
  int* row_ptr = (int*)alloc((size_t)(NN + 1) * 4);
  int* bsum    = (int*)alloc(64 * 4);
  int2* esw    = (int2*)alloc((size_t)NE * 8);
  ushort* bufA = (ushort*)alloc((size_t)NN * KH * 2);
  ushort* bufB = (ushort*)alloc((size_t)NN * KH * 2);
  ushort* Wt1  = (ushort*)alloc((size_t)CH * KH * 2);
  ushort* Wt2  = (ushort*)alloc((size_t)CH * KH * 2);
  ushort* Wt3v = (ushort*)alloc((size_t)80 * CH * 2);
  float* pooled = (float*)alloc((size_t)NG * CO * 4);
  float* cnts   = (float*)alloc((size_t)NG * 4);

  // layer-3 scratch aliases into bufB (free after layer-2 GEMM consumes it)
  ushort* V   = bufB;                       // [NN][80] bf16
  ushort* bb3 = bufB + (size_t)NN * 80;     // [NN][16] bf16
  ushort* bb2 = bb3 + (size_t)NN * CO;
  ushort* bb1 = bb2 + (size_t)NN * CO;
  float*  H3  = (float*)(bb1 + (size_t)NN * CO);  // [NN][16] f32

  hipMemsetAsync(deg, 0, (size_t)NN * 4, stream);
  hipMemsetAsync(hist, 0, (size_t)NN * 4, stream);
  hipMemsetAsync(fill, 0, (size_t)NN * 4, stream);
  hipMemsetAsync(pooled, 0, (size_t)NG * CO * 4, stream);
  hipMemsetAsync(cnts, 0, (size_t)NG * 4, stream);

  int egrid = (NE + 255) / 256;
  int nsb = (NN + 1023) / 1024;
  k_hist<<<egrid, 256, 0, stream>>>(src, dst, deg, hist, NE);
  k_scan_a<<<nsb, 1024, 0, stream>>>(hist, row_ptr, bsum, NN);
  k_scan_b<<<1, 64, 0, stream>>>(bsum, nsb);
  k_scan_c<<<nsb, 1024, 0, stream>>>(bsum, row_ptr, NN);
  k_scatter<<<egrid, 256, 0, stream>>>(src, dst, deg, row_ptr, fill, esw, NE);

  k_cvt_x<<<(NN * 64 + 255) / 256, 256, 0, stream>>>(x, bufA);
  k_cvt_w<<<(KH * CH + 255) / 256, 256, 0, stream>>>(W1, Wt1, CH);
  k_cvt_w<<<(KH * CH + 255) / 256, 256, 0, stream>>>(W2, Wt2, CH);
  k_cvt_w3<<<(5 * CH * CO + 255) / 256, 256, 0, stream>>>(W3, Wt3v);

  dim3 gg128((NN + 127) / 128);
  dim3 gg256((NN + 255) / 256);
  dim3 gp4((NN + 3) / 4);

  // layer 1: bufA slices -> bufB slice0 (relu)
  run_props(bufA, row_ptr, esw, stream);
  k_gemm_mfma128<<<gg128, 256, 0, stream>>>(bufA, Wt1, b1, bufB, NN, 1);

  // layer 2: bufB slices -> bufA slice0 (relu)
  run_props(bufB, row_ptr, esw, stream);
  k_gemm_mfma128<<<gg128, 256, 0, stream>>>(bufB, Wt2, b2, bufA, NN, 1);

  // layer 3 via Clenshaw: V = h2 @ W3cat; b_k = 2L b_{k+1} - b_{k+2} + v_k
  k_gemm_v<<<gg256, 256, 0, stream>>>(bufA, Wt3v, V, NN);
  k_prop16<<<gp4, 256, 0, stream>>>(V + 64, 80, nullptr, 0, V + 48, 80, nullptr,
                                    bb3, nullptr, 2.f, row_ptr, esw, NN);
  k_prop16<<<gp4, 256, 0, stream>>>(bb3, CO, V + 64, 80, V + 32, 80, nullptr,
                                    bb2, nullptr, 2.f, row_ptr, esw, NN);
  k_prop16<<<gp4, 256, 0, stream>>>(bb2, CO, bb3, CO, V + 16, 80, nullptr,
                                    bb1, nullptr, 2.f, row_ptr, esw, NN);
  k_prop16<<<gp4, 256, 0, stream>>>(bb1, CO, bb2, CO, V + 0, 80, b3,
                                    nullptr, H3, 1.f, row_ptr, esw, NN);

  // pool + log_softmax
  int pgrid = (NN + 1023) / 1024;
  k_pool<<<pgrid, 256, 0, stream>>>(H3, batch, pooled, cnts, NN);
  k_lsm<<<1, 64, 0, stream>>>(pooled, cnts, out);
}

// Round 5
// 631.163 us; speedup vs baseline: 1.6115x; 1.6115x over previous
//
#include <hip/hip_runtime.h>
#include <stdint.h>

#define NN 50000
#define NE 800000
#define NG 64
#define CH 128
#define CO 16
#define KH 640   // 5 * 128

typedef __attribute__((ext_vector_type(8))) short bf16x8;
typedef __attribute__((ext_vector_type(4))) float f32x4;

__device__ __forceinline__ ushort f2bf(float f) {
  uint32_t u = __float_as_uint(f);
  u += 0x7fffu + ((u >> 16) & 1u);
  return (ushort)(u >> 16);
}
__device__ __forceinline__ float bflo(uint32_t v) { return __uint_as_float(v << 16); }
__device__ __forceinline__ float bfhi(uint32_t v) { return __uint_as_float(v & 0xffff0000u); }

// ---------------- graph preprocessing ----------------

__global__ void k_hist(const int* __restrict__ src, const int* __restrict__ dst,
                       int* __restrict__ deg, int* __restrict__ hist, int E) {
  int e = blockIdx.x * blockDim.x + threadIdx.x;
  if (e < E) {
    atomicAdd(&deg[src[e]], 1);
    atomicAdd(&hist[dst[e]], 1);
  }
}

__global__ __launch_bounds__(1024) void k_scan_a(const int* __restrict__ hist,
                                                 int* __restrict__ row_ptr,
                                                 int* __restrict__ bsum, int n) {
  __shared__ int sm[1024];
  int i = blockIdx.x * 1024 + threadIdx.x;
  int v = (i < n) ? hist[i] : 0;
  sm[threadIdx.x] = v;
  __syncthreads();
  for (int off = 1; off < 1024; off <<= 1) {
    int t = (threadIdx.x >= off) ? sm[threadIdx.x - off] : 0;
    __syncthreads();
    sm[threadIdx.x] += t;
    __syncthreads();
  }
  if (i < n) row_ptr[i + 1] = sm[threadIdx.x];
  if (threadIdx.x == 1023) bsum[blockIdx.x] = sm[1023];
}

__global__ void k_scan_b(int* __restrict__ bsum, int nb) {
  if (threadIdx.x == 0) {
    int off = 0;
    for (int i = 0; i < nb; ++i) { int t = bsum[i]; bsum[i] = off; off += t; }
  }
}

__global__ __launch_bounds__(1024) void k_scan_c(const int* __restrict__ bsum,
                                                 int* __restrict__ row_ptr, int n) {
  int i = blockIdx.x * 1024 + threadIdx.x;
  if (i == 0) row_ptr[0] = 0;
  if (i < n) row_ptr[i + 1] += bsum[blockIdx.x];
}

__global__ void k_scatter(const int* __restrict__ src, const int* __restrict__ dst,
                          const int* __restrict__ deg, const int* __restrict__ row_ptr,
                          int* __restrict__ fill, int2* __restrict__ esw, int E) {
  int e = blockIdx.x * blockDim.x + threadIdx.x;
  if (e < E) {
    int s = src[e], d = dst[e];
    int ds = deg[s], dd = deg[d];
    float di = ds > 0 ? rsqrtf((float)ds) : 0.f;
    float dj = dd > 0 ? rsqrtf((float)dd) : 0.f;
    float w = -di * dj;
    int pos = row_ptr[d] + atomicAdd(&fill[d], 1);
    int2 p; p.x = s; p.y = __float_as_int(w);
    esw[pos] = p;
  }
}

// ---------------- conversions ----------------

__global__ __launch_bounds__(256) void k_cvt_x(const float* __restrict__ x,
                                               ushort* __restrict__ buf) {
  int t = blockIdx.x * 256 + threadIdx.x;       // over NN*64 float2's
  if (t >= NN * 64) return;
  int node = t >> 6, p = t & 63;
  float2 v = reinterpret_cast<const float2*>(x)[t];
  uint32_t w = (uint32_t)f2bf(v.x) | ((uint32_t)f2bf(v.y) << 16);
  *reinterpret_cast<uint32_t*>(buf + (size_t)node * KH + p * 2) = w;
}

// W [640][cout] f32 -> Wt [cout][640] bf16
__global__ __launch_bounds__(256) void k_cvt_w(const float* __restrict__ W,
                                               ushort* __restrict__ Wt, int cout) {
  int t = blockIdx.x * 256 + threadIdx.x;
  if (t >= KH * cout) return;
  int kc = t / cout, nc = t - kc * cout;
  Wt[(size_t)nc * KH + kc] = f2bf(W[t]);
}

// W3 [5][128][16] f32 -> Wt3v [80][128] bf16 : Wt3v[k*16+j][c] = W3[k][c][j]
__global__ __launch_bounds__(256) void k_cvt_w3(const float* __restrict__ W,
                                                ushort* __restrict__ Wt) {
  int t = blockIdx.x * 256 + threadIdx.x;
  if (t >= 5 * CH * CO) return;
  int k = t / (CH * CO);
  int r = t - k * CH * CO;
  int c = r / CO, j = r - c * CO;
  Wt[(size_t)(k * CO + j) * CH + c] = f2bf(W[t]);
}

// ---------------- propagation (bf16, 128 ch), edge-parallel wide gathers ----
// wave = 1 dst node; 4 edge-groups x 16 lanes x 16B (uint4 = 8ch) -> each
// wave-instruction gathers 4 full 256B source rows. out = 2*L(hin) - tx0.

__global__ __launch_bounds__(256) void k_prop_bf(
    const ushort* __restrict__ hin, const ushort* __restrict__ tx0,
    ushort* __restrict__ hout, const int* __restrict__ row_ptr,
    const int2* __restrict__ esw, int n) {
  int wave = threadIdx.x >> 6;
  int lane = threadIdx.x & 63;
  int node = blockIdx.x * 4 + wave;
  if (node >= n) return;
  int beg = row_ptr[node], end = row_ptr[node + 1];
  int grp = lane >> 4, li = lane & 15;
  const ushort* hc = hin + li * 8;

  float a0 = 0.f, a1 = 0.f, a2 = 0.f, a3 = 0.f;
  float a4 = 0.f, a5 = 0.f, a6 = 0.f, a7 = 0.f;

  for (int e0 = beg; e0 < end; e0 += 8) {
    int ea = e0 + grp, eb = e0 + 4 + grp;
    int2 pa = esw[min(ea, NE - 1)];
    int2 pb = esw[min(eb, NE - 1)];
    float wa = (ea < end) ? __int_as_float(pa.y) : 0.f;
    float wb = (eb < end) ? __int_as_float(pb.y) : 0.f;
    const uint4 va = *reinterpret_cast<const uint4*>(hc + (size_t)pa.x * KH);
    const uint4 vb = *reinterpret_cast<const uint4*>(hc + (size_t)pb.x * KH);
    a0 = fmaf(wa, bflo(va.x), a0);
    a1 = fmaf(wa, bfhi(va.x), a1);
    a2 = fmaf(wa, bflo(va.y), a2);
    a3 = fmaf(wa, bfhi(va.y), a3);
    a4 = fmaf(wa, bflo(va.z), a4);
    a5 = fmaf(wa, bfhi(va.z), a5);
    a6 = fmaf(wa, bflo(va.w), a6);
    a7 = fmaf(wa, bfhi(va.w), a7);
    a0 = fmaf(wb, bflo(vb.x), a0);
    a1 = fmaf(wb, bfhi(vb.x), a1);
    a2 = fmaf(wb, bflo(vb.y), a2);
    a3 = fmaf(wb, bfhi(vb.y), a3);
    a4 = fmaf(wb, bflo(vb.z), a4);
    a5 = fmaf(wb, bfhi(vb.z), a5);
    a6 = fmaf(wb, bflo(vb.w), a6);
    a7 = fmaf(wb, bfhi(vb.w), a7);
  }

  // reduce the 4 edge-groups (lanes l, l+16, l+32, l+48 hold same channels)
  a0 += __shfl_xor(a0, 16, 64); a1 += __shfl_xor(a1, 16, 64);
  a2 += __shfl_xor(a2, 16, 64); a3 += __shfl_xor(a3, 16, 64);
  a4 += __shfl_xor(a4, 16, 64); a5 += __shfl_xor(a5, 16, 64);
  a6 += __shfl_xor(a6, 16, 64); a7 += __shfl_xor(a7, 16, 64);
  a0 += __shfl_xor(a0, 32, 64); a1 += __shfl_xor(a1, 32, 64);
  a2 += __shfl_xor(a2, 32, 64); a3 += __shfl_xor(a3, 32, 64);
  a4 += __shfl_xor(a4, 32, 64); a5 += __shfl_xor(a5, 32, 64);
  a6 += __shfl_xor(a6, 32, 64); a7 += __shfl_xor(a7, 32, 64);

  if (grp == 0) {
    size_t o = (size_t)node * KH + li * 8;
    if (tx0) {
      const uint4 t = *reinterpret_cast<const uint4*>(tx0 + o);
      a0 = 2.f * a0 - bflo(t.x);
      a1 = 2.f * a1 - bfhi(t.x);
      a2 = 2.f * a2 - bflo(t.y);
      a3 = 2.f * a3 - bfhi(t.y);
      a4 = 2.f * a4 - bflo(t.z);
      a5 = 2.f * a5 - bfhi(t.z);
      a6 = 2.f * a6 - bflo(t.w);
      a7 = 2.f * a7 - bfhi(t.w);
    }
    uint4 w;
    w.x = (uint32_t)f2bf(a0) | ((uint32_t)f2bf(a1) << 16);
    w.y = (uint32_t)f2bf(a2) | ((uint32_t)f2bf(a3) << 16);
    w.z = (uint32_t)f2bf(a4) | ((uint32_t)f2bf(a5) << 16);
    w.w = (uint32_t)f2bf(a6) | ((uint32_t)f2bf(a7) << 16);
    *reinterpret_cast<uint4*>(hout + o) = w;
  }
}

// ---------------- propagation (bf16, 16 ch) with Clenshaw combine ----------------
// r = scale*L(gin) - prev + v  [+ bias -> f32 out]

__global__ __launch_bounds__(256) void k_prop16(
    const ushort* __restrict__ gin, int gstride,
    const ushort* __restrict__ prev, int pstride,
    const ushort* __restrict__ v, int vstride,
    const float* __restrict__ bias,
    ushort* __restrict__ bout, float* __restrict__ fout,
    float scale, const int* __restrict__ row_ptr,
    const int2* __restrict__ esw, int n) {
  int wave = threadIdx.x >> 6;
  int lane = threadIdx.x & 63;
  int node = blockIdx.x * 4 + wave;
  if (node >= n) return;
  int beg = row_ptr[node], end = row_ptr[node + 1];
  int ch2 = lane & 7;       // uint index over 16 channels
  int grp = lane >> 3;      // 8 edge subgroups
  float ax = 0.f, ay = 0.f;
  const ushort* gc = gin + ch2 * 2;
  for (int e = beg + grp; e < end; e += 8) {
    int2 p = esw[e];
    float w = __int_as_float(p.y);
    uint32_t vv = *reinterpret_cast<const uint32_t*>(gc + (size_t)p.x * gstride);
    ax = fmaf(w, bflo(vv), ax);
    ay = fmaf(w, bfhi(vv), ay);
  }
#pragma unroll
  for (int off = 8; off < 64; off <<= 1) {
    ax += __shfl_xor(ax, off, 64);
    ay += __shfl_xor(ay, off, 64);
  }
  if (lane < 8) {
    float rx = scale * ax, ry = scale * ay;
    if (prev) {
      uint32_t pv = *reinterpret_cast<const uint32_t*>(prev + (size_t)node * pstride + lane * 2);
      rx -= bflo(pv);
      ry -= bfhi(pv);
    }
    uint32_t vv = *reinterpret_cast<const uint32_t*>(v + (size_t)node * vstride + lane * 2);
    rx += bflo(vv);
    ry += bfhi(vv);
    if (fout) {
      fout[(size_t)node * CO + lane * 2]     = rx + bias[lane * 2];
      fout[(size_t)node * CO + lane * 2 + 1] = ry + bias[lane * 2 + 1];
    } else {
      uint32_t w = (uint32_t)f2bf(rx) | ((uint32_t)f2bf(ry) << 16);
      *reinterpret_cast<uint32_t*>(bout + (size_t)node * CO + lane * 2) = w;
    }
  }
}

// ---------------- MFMA GEMM: out slice = A[n x 640] @ W[640 x 128] + bias, relu

__global__ __launch_bounds__(256) void k_gemm_mfma128(
    const ushort* __restrict__ A, const ushort* __restrict__ Wt,
    const float* __restrict__ bias, ushort* __restrict__ outbf,
    int n, int dorelu) {
  int wave = threadIdx.x >> 6, lane = threadIdx.x & 63;
  int rowbase = blockIdx.x * 128 + wave * 32;
  int lr = lane & 15, lk = (lane >> 4) * 8;

  f32x4 acc[2][8];
#pragma unroll
  for (int r = 0; r < 2; ++r)
#pragma unroll
    for (int c = 0; c < 8; ++c) acc[r][c] = (f32x4){0.f, 0.f, 0.f, 0.f};

  int r0 = min(rowbase + lr, n - 1);
  int r1 = min(rowbase + 16 + lr, n - 1);
  const ushort* pa0 = A + (size_t)r0 * KH + lk;
  const ushort* pa1 = A + (size_t)r1 * KH + lk;
  const ushort* pb = Wt + (size_t)lr * KH + lk;

  for (int k0 = 0; k0 < KH; k0 += 32) {
    bf16x8 a0 = *reinterpret_cast<const bf16x8*>(pa0 + k0);
    bf16x8 a1 = *reinterpret_cast<const bf16x8*>(pa1 + k0);
#pragma unroll
    for (int c = 0; c < 8; ++c) {
      bf16x8 b = *reinterpret_cast<const bf16x8*>(pb + (size_t)c * 16 * KH + k0);
      acc[0][c] = __builtin_amdgcn_mfma_f32_16x16x32_bf16(a0, b, acc[0][c], 0, 0, 0);
      acc[1][c] = __builtin_amdgcn_mfma_f32_16x16x32_bf16(a1, b, acc[1][c], 0, 0, 0);
    }
  }

#pragma unroll
  for (int r = 0; r < 2; ++r) {
#pragma unroll
    for (int c = 0; c < 8; ++c) {
      int col = c * 16 + lr;
      float bs = bias[col];
#pragma unroll
      for (int i = 0; i < 4; ++i) {
        int row = rowbase + r * 16 + (lane >> 4) * 4 + i;
        if (row < n) {
          float v = acc[r][c][i] + bs;
          if (dorelu) v = fmaxf(v, 0.f);
          outbf[(size_t)row * KH + col] = f2bf(v);
        }
      }
    }
  }
}

// V[n x 80] bf16 = A[n x 128] @ Wt3v^T  (Wt3v [80][128])
__global__ __launch_bounds__(256) void k_gemm_v(
    const ushort* __restrict__ A, const ushort* __restrict__ Wt,
    ushort* __restrict__ V, int n) {
  int wave = threadIdx.x >> 6, lane = threadIdx.x & 63;
  int rowbase = blockIdx.x * 256 + wave * 64;
  int lr = lane & 15, lk = (lane >> 4) * 8;

  f32x4 acc[4][5];
#pragma unroll
  for (int r = 0; r < 4; ++r)
#pragma unroll
    for (int c = 0; c < 5; ++c) acc[r][c] = (f32x4){0.f, 0.f, 0.f, 0.f};

  const ushort* pa[4];
#pragma unroll
  for (int r = 0; r < 4; ++r) {
    int rr = min(rowbase + r * 16 + lr, n - 1);
    pa[r] = A + (size_t)rr * KH + lk;
  }
  const ushort* pb = Wt + (size_t)lr * CH + lk;

  for (int k0 = 0; k0 < CH; k0 += 32) {
    bf16x8 a[4];
#pragma unroll
    for (int r = 0; r < 4; ++r) a[r] = *reinterpret_cast<const bf16x8*>(pa[r] + k0);
#pragma unroll
    for (int c = 0; c < 5; ++c) {
      bf16x8 b = *reinterpret_cast<const bf16x8*>(pb + (size_t)c * 16 * CH + k0);
#pragma unroll
      for (int r = 0; r < 4; ++r)
        acc[r][c] = __builtin_amdgcn_mfma_f32_16x16x32_bf16(a[r], b, acc[r][c], 0, 0, 0);
    }
  }

#pragma unroll
  for (int r = 0; r < 4; ++r) {
#pragma unroll
    for (int c = 0; c < 5; ++c) {
      int col = c * 16 + lr;
#pragma unroll
      for (int i = 0; i < 4; ++i) {
        int row = rowbase + r * 16 + (lane >> 4) * 4 + i;
        if (row < n) V[(size_t)row * 80 + col] = f2bf(acc[r][c][i]);
      }
    }
  }
}

// ---------------- pooling + log_softmax ----------------

__global__ __launch_bounds__(256) void k_pool(
    const float* __restrict__ h, const int* __restrict__ batch,
    float* __restrict__ sums, float* __restrict__ cnts, int n) {
  __shared__ float sacc[NG * CO];
  __shared__ float scnt[NG];
  for (int i = threadIdx.x; i < NG * CO; i += 256) sacc[i] = 0.f;
  if (threadIdx.x < NG) scnt[threadIdx.x] = 0.f;
  __syncthreads();
  int ch = threadIdx.x & 15;
  int nl = threadIdx.x >> 4;
  int base = blockIdx.x * 1024;
  for (int i = 0; i < 64; ++i) {
    int node = base + i * 16 + nl;
    if (node < n) {
      int g = batch[node];
      atomicAdd(&sacc[g * CO + ch], h[(size_t)node * CO + ch]);
      if (ch == 0) atomicAdd(&scnt[g], 1.f);
    }
  }
  __syncthreads();
  for (int i = threadIdx.x; i < NG * CO; i += 256)
    if (sacc[i] != 0.f) atomicAdd(&sums[i], sacc[i]);
  if (threadIdx.x < NG && scnt[threadIdx.x] != 0.f)
    atomicAdd(&cnts[threadIdx.x], scnt[threadIdx.x]);
}

__global__ void k_lsm(const float* __restrict__ sums, const float* __restrict__ cnts,
                      float* __restrict__ out) {
  int g = threadIdx.x;
  if (g >= NG) return;
  float cnt = fmaxf(cnts[g], 1.f);
  float v[CO];
  float m = -1e30f;
#pragma unroll
  for (int c = 0; c < CO; ++c) { v[c] = sums[g * CO + c] / cnt; m = fmaxf(m, v[c]); }
  float s = 0.f;
#pragma unroll
  for (int c = 0; c < CO; ++c) s += expf(v[c] - m);
  float lse = m + logf(s);
#pragma unroll
  for (int c = 0; c < CO; ++c) out[g * CO + c] = v[c] - lse;
}

// ---------------- host ----------------

static void run_props(ushort* buf, const int* row_ptr, const int2* esw,
                      hipStream_t stream) {
  dim3 gp((NN + 3) / 4);
  k_prop_bf<<<gp, 256, 0, stream>>>(buf + 0 * CH, nullptr,      buf + 1 * CH, row_ptr, esw, NN);
  k_prop_bf<<<gp, 256, 0, stream>>>(buf + 1 * CH, buf + 0 * CH, buf + 2 * CH, row_ptr, esw, NN);
  k_prop_bf<<<gp, 256, 0, stream>>>(buf + 2 * CH, buf + 1 * CH, buf + 3 * CH, row_ptr, esw, NN);
  k_prop_bf<<<gp, 256, 0, stream>>>(buf + 3 * CH, buf + 2 * CH, buf + 4 * CH, row_ptr, esw, NN);
}

extern "C" void kernel_launch(void* const* d_in, const int* in_sizes, int n_in,
                              void* d_out, int out_size, void* d_ws, size_t ws_size,
                              hipStream_t stream) {
  const float* x   = (const float*)d_in[0];
  const int* src   = (const int*)d_in[1];
  const int* dst   = (const int*)d_in[2];
  const int* batch = (const int*)d_in[3];
  const float* W1  = (const float*)d_in[4];
  const float* b1  = (const float*)d_in[5];
  const float* W2  = (const float*)d_in[6];
  const float* b2  = (const float*)d_in[7];
  const float* W3  = (const float*)d_in[8];
  const float* b3  = (const float*)d_in[9];
  float* out = (float*)d_out;

  char* p = (char*)d_ws;
  auto alloc = [&](size_t bytes) -> void* {
    void* r = (void*)p;
    p += (bytes + 511) & ~(size_t)511;
    return r;
  };
  int* deg     = (int*)alloc((size_t)NN * 4);
  int* hist    = (int*)alloc((size_t)NN * 4);
  int* fill    = (int*)alloc((size_t)NN * 4);
  int* row_ptr = (int*)alloc((size_t)(NN + 1) * 4);
  int* bsum    = (int*)alloc(64 * 4);
  int2* esw    = (int2*)alloc((size_t)NE * 8);
  ushort* bufA = (ushort*)alloc((size_t)NN * KH * 2);
  ushort* bufB = (ushort*)alloc((size_t)NN * KH * 2);
  ushort* Wt1  = (ushort*)alloc((size_t)CH * KH * 2);
  ushort* Wt2  = (ushort*)alloc((size_t)CH * KH * 2);
  ushort* Wt3v = (ushort*)alloc((size_t)80 * CH * 2);
  float* pooled = (float*)alloc((size_t)NG * CO * 4);
  float* cnts   = (float*)alloc((size_t)NG * 4);

  // layer-3 scratch aliases into bufB (free after layer-2 GEMM consumes it)
  ushort* V   = bufB;                       // [NN][80] bf16
  ushort* bb3 = bufB + (size_t)NN * 80;     // [NN][16] bf16
  ushort* bb2 = bb3 + (size_t)NN * CO;
  ushort* bb1 = bb2 + (size_t)NN * CO;
  float*  H3  = (float*)(bb1 + (size_t)NN * CO);  // [NN][16] f32

  hipMemsetAsync(deg, 0, (size_t)NN * 4, stream);
  hipMemsetAsync(hist, 0, (size_t)NN * 4, stream);
  hipMemsetAsync(fill, 0, (size_t)NN * 4, stream);
  hipMemsetAsync(pooled, 0, (size_t)NG * CO * 4, stream);
  hipMemsetAsync(cnts, 0, (size_t)NG * 4, stream);

  int egrid = (NE + 255) / 256;
  int nsb = (NN + 1023) / 1024;
  k_hist<<<egrid, 256, 0, stream>>>(src, dst, deg, hist, NE);
  k_scan_a<<<nsb, 1024, 0, stream>>>(hist, row_ptr, bsum, NN);
  k_scan_b<<<1, 64, 0, stream>>>(bsum, nsb);
  k_scan_c<<<nsb, 1024, 0, stream>>>(bsum, row_ptr, NN);
  k_scatter<<<egrid, 256, 0, stream>>>(src, dst, deg, row_ptr, fill, esw, NE);

  k_cvt_x<<<(NN * 64 + 255) / 256, 256, 0, stream>>>(x, bufA);
  k_cvt_w<<<(KH * CH + 255) / 256, 256, 0, stream>>>(W1, Wt1, CH);
  k_cvt_w<<<(KH * CH + 255) / 256, 256, 0, stream>>>(W2, Wt2, CH);
  k_cvt_w3<<<(5 * CH * CO + 255) / 256, 256, 0, stream>>>(W3, Wt3v);

  dim3 gg128((NN + 127) / 128);
  dim3 gg256((NN + 255) / 256);
  dim3 gp4((NN + 3) / 4);

  // layer 1: bufA slices -> bufB slice0 (relu)
  run_props(bufA, row_ptr, esw, stream);
  k_gemm_mfma128<<<gg128, 256, 0, stream>>>(bufA, Wt1, b1, bufB, NN, 1);

  // layer 2: bufB slices -> bufA slice0 (relu)
  run_props(bufB, row_ptr, esw, stream);
  k_gemm_mfma128<<<gg128, 256, 0, stream>>>(bufB, Wt2, b2, bufA, NN, 1);

  // layer 3 via Clenshaw: V = h2 @ W3cat; b_k = 2L b_{k+1} - b_{k+2} + v_k
  k_gemm_v<<<gg256, 256, 0, stream>>>(bufA, Wt3v, V, NN);
  k_prop16<<<gp4, 256, 0, stream>>>(V + 64, 80, nullptr, 0, V + 48, 80, nullptr,
                                    bb3, nullptr, 2.f, row_ptr, esw, NN);
  k_prop16<<<gp4, 256, 0, stream>>>(bb3, CO, V + 64, 80, V + 32, 80, nullptr,
                                    bb2, nullptr, 2.f, row_ptr, esw, NN);
  k_prop16<<<gp4, 256, 0, stream>>>(bb2, CO, bb3, CO, V + 16, 80, nullptr,
                                    bb1, nullptr, 2.f, row_ptr, esw, NN);
  k_prop16<<<gp4, 256, 0, stream>>>(bb1, CO, bb2, CO, V + 0, 80, b3,
                                    nullptr, H3, 1.f, row_ptr, esw, NN);

  // pool + log_softmax
  int pgrid = (NN + 1023) / 1024;
  k_pool<<<pgrid, 256, 0, stream>>>(H3, batch, pooled, cnts, NN);
  k_lsm<<<1, 64, 0, stream>>>(pooled, cnts, out);
}